// Round 3
// baseline (137.483 us; speedup 1.0000x reference)
//
#include <hip/hip_runtime.h>
#include <hip/hip_bf16.h>

#define NN 1024
#define EE 4096
#define CC 32     // channels C
#define SD 16     // SUM_DIM
#define FQ 44     // FREQ_SUM
#define MIDC 32   // MLP mid
#define EB 16     // edges per workgroup
#define NFQ 2     // f-range split
#define FPB 22    // f per block

typedef short s16x4 __attribute__((ext_vector_type(4)));
typedef short s16x8 __attribute__((ext_vector_type(8)));
typedef float fx4 __attribute__((ext_vector_type(4)));

__device__ __forceinline__ unsigned short f2b(float x) {
    __hip_bfloat16 b = __float2bfloat16(x);
    return *reinterpret_cast<unsigned short*>(&b);
}

// ---------------- K0: w3 (m, o*1408 + c*44 + f) -> w3t2[f][o][c][m] bf16 ----------------
__global__ __launch_bounds__(256) void k_w3t2(const float* __restrict__ w3,
                                              unsigned short* __restrict__ w3t2) {
    int tid = blockIdx.x * 256 + threadIdx.x;   // 32768 threads
    int m = tid & 31;
    int o = (tid >> 5) & 31;
    int c = tid >> 10;
    const float* rp = &w3[(size_t)m * 45056 + o * 1408 + c * 44];
    float v[44];
#pragma unroll
    for (int q = 0; q < 11; q++) {
        float4 t4 = *(const float4*)(rp + q * 4);
        v[q * 4 + 0] = t4.x; v[q * 4 + 1] = t4.y;
        v[q * 4 + 2] = t4.z; v[q * 4 + 3] = t4.w;
    }
#pragma unroll
    for (int f = 0; f < FQ; f++) {
        w3t2[(((size_t)f * CC + o) * CC + c) * CC + m] = f2b(v[f]);
    }
}

// ---------------- K1: h2 = bf16(relu(relu(inv@w1+b1)@w2+b2)), deg counts ----------------
__global__ __launch_bounds__(256) void k_h(const float* __restrict__ ef,
                                           const float* __restrict__ w1,
                                           const float* __restrict__ b1,
                                           const float* __restrict__ w2,
                                           const float* __restrict__ b2,
                                           const int* __restrict__ dst,
                                           unsigned short* __restrict__ h2,
                                           int* __restrict__ deg) {
    int e = blockIdx.x * 256 + threadIdx.x;
    if (e >= EE) return;
    float i0 = ef[e * 2 + 0], i1 = ef[e * 2 + 1];
    float h1[MIDC];
#pragma unroll
    for (int j = 0; j < MIDC; j++) {
        float v = i0 * w1[j] + i1 * w1[MIDC + j] + b1[j];
        h1[j] = v > 0.f ? v : 0.f;
    }
    for (int j = 0; j < MIDC; j++) {
        float v = b2[j];
#pragma unroll
        for (int m = 0; m < MIDC; m++) v += h1[m] * w2[m * MIDC + j];
        v = v > 0.f ? v : 0.f;
        h2[e * MIDC + j] = f2b(v);
    }
    atomicAdd(&deg[dst[e]], 1);
}

// ---------------- K2: fused MFMA main kernel ----------------
// grid = 512: blockIdx -> (e-group of 16) x (f-half of 22). 512 threads = 8 waves.
// Per wave: 2 edges. Basis B-fragments loaded DIRECTLY from global (prefetched 1 f ahead).
__global__ __launch_bounds__(512, 4) void k_main(
    const float* __restrict__ nf0, const float* __restrict__ nf1,
    const float* __restrict__ nf2, const float* __restrict__ nf3,
    const float* __restrict__ basis, const int* __restrict__ src,
    const int* __restrict__ dst, const unsigned short* __restrict__ h2,
    const unsigned short* __restrict__ w3t2, float* __restrict__ out) {
    __shared__ __align__(16) unsigned short rad_lds[EB * CC * CC];   // 32768 B (swizzled)
    __shared__ __align__(16) unsigned short u_scr[16 * 640];         // 20480 B: (wv,ei) x [s16][40]

    int t = threadIdx.x;
    int wv = t >> 6;
    int l = t & 63;
    int l15 = l & 15;
    int kg = l >> 4;            // k-group 0..3
    int eg = blockIdx.x >> 1;
    int fq = blockIdx.x & 1;
    int eb = eg * EB;
    int f0 = fq * FPB;

    // ---- setup: gather feats (f32) into fstage (aliases rad_lds: 8192 floats) ----
    float* fstage = (float*)rad_lds;
    {
        int e = t >> 5, c = t & 31;
        int sn = src[eb + e];
        float* row = &fstage[(e * CC + c) * SD];
        row[0] = nf0[sn * CC + c];
#pragma unroll
        for (int j = 0; j < 3; j++) row[1 + j] = nf1[(sn * CC + c) * 3 + j];
#pragma unroll
        for (int j = 0; j < 5; j++) row[4 + j] = nf2[(sn * CC + c) * 5 + j];
#pragma unroll
        for (int j = 0; j < 7; j++) row[9 + j] = nf3[(sn * CC + c) * 7 + j];
    }
    // h2 fragment (B of rad mfma): lane: e = l15, k = m in [kg*8, kg*8+8)
    s16x8 h2frag = *(const s16x8*)(h2 + ((size_t)(eb + l15) * MIDC + (kg << 3)));
    __syncthreads();

    // ---- feats fragments (A of U mfma, K=32 with i>=16 zero-padded) ----
    s16x8 feats[2][2];
#pragma unroll
    for (int ei = 0; ei < 2; ei++) {
        int e = (wv << 1) + ei;
#pragma unroll
        for (int ch = 0; ch < 2; ch++) {
            s16x8 fr = {};
            if (kg < 2) {
                const float4* fp4 =
                    (const float4*)&fstage[(e * CC + (ch << 4) + l15) * SD + (kg << 3)];
                float4 a = fp4[0], b = fp4[1];
                fr[0] = (short)f2b(a.x); fr[1] = (short)f2b(a.y);
                fr[2] = (short)f2b(a.z); fr[3] = (short)f2b(a.w);
                fr[4] = (short)f2b(b.x); fr[5] = (short)f2b(b.y);
                fr[6] = (short)f2b(b.z); fr[7] = (short)f2b(b.w);
            }
            feats[ei][ch] = fr;
        }
    }
    __syncthreads();   // fstage reads done before rad_lds writes

    fx4 acc[2][2];
#pragma unroll
    for (int q = 0; q < 4; q++) acc[q >> 1][q & 1] = (fx4){0.f, 0.f, 0.f, 0.f};
    fx4 zz = (fx4){0.f, 0.f, 0.f, 0.f};

    // basis prefetch regs: pf[ei][j] = basis[e][i=kg*8+j][f][s=l15]  (lanes kg<2 only)
    float pf[2][8];
#define ISSUE_PF(FNEXT)                                                                   \
    if (kg < 2) {                                                                         \
        _Pragma("unroll") for (int ei = 0; ei < 2; ei++) {                                \
            int e_ = (wv << 1) + ei;                                                      \
            const float* bp =                                                             \
                &basis[(((size_t)(eb + e_) * SD + (kg << 3)) * FQ + (FNEXT)) * SD + l15]; \
            _Pragma("unroll") for (int j = 0; j < 8; j++)                                 \
                pf[ei][j] = bp[(size_t)j * (FQ * SD)];                                    \
        }                                                                                 \
    }

    ISSUE_PF(f0);

    s16x8 bb[2];

    for (int fi = 0; fi < FPB; fi++) {
        int f = f0 + fi;

        // ---- phase 1: rad tiles  C[(c)-16][e-16] = w3t2[f][o] @ h2, for o = wv*4..+3 ----
#pragma unroll
        for (int j = 0; j < 8; j++) {
            int o = (wv << 2) + (j >> 1);
            int ch = j & 1;
            s16x8 af = *(const s16x8*)(w3t2 +
                ((((size_t)f * CC + o) * CC + (ch << 4) + l15) * CC + (kg << 3)));
            fx4 cf = __builtin_amdgcn_mfma_f32_16x16x32_bf16(af, h2frag, zz, 0, 0, 0);
            int byte = (l15 << 11) + (o << 6) + (ch << 5) + (kg << 3);
            byte ^= ((l15 ^ o) & 7) << 4;
            s16x4 pk;
            pk[0] = (short)f2b(cf[0]); pk[1] = (short)f2b(cf[1]);
            pk[2] = (short)f2b(cf[2]); pk[3] = (short)f2b(cf[3]);
            *(s16x4*)((char*)rad_lds + byte) = pk;
        }

        // ---- convert prefetched basis -> bb (B of U mfma; kg>=2 lanes = zero pad) ----
#pragma unroll
        for (int ei = 0; ei < 2; ei++) {
            s16x8 b = {};
            if (kg < 2) {
#pragma unroll
                for (int j = 0; j < 8; j++) b[j] = (short)f2b(pf[ei][j]);
            }
            bb[ei] = b;
        }
        __syncthreads();

        // ---- phase 2 ----
        if (fi + 1 < FPB) { ISSUE_PF(f + 1); }   // overlap loads with MFMA below

        // U mfmas (per edge): D_u[c-tile][s], then same-wave LDS round trip to
        // re-shape into the final mfma's B fragment (k=c packed by 8).
        fx4 u[2][2];
#pragma unroll
        for (int ei = 0; ei < 2; ei++) {
#pragma unroll
            for (int ch = 0; ch < 2; ch++)
                u[ei][ch] = __builtin_amdgcn_mfma_f32_16x16x32_bf16(feats[ei][ch], bb[ei], zz, 0, 0, 0);
        }
#pragma unroll
        for (int ei = 0; ei < 2; ei++) {
            int rbase = ((wv << 1) + ei) * 1280;
#pragma unroll
            for (int ch = 0; ch < 2; ch++) {
                s16x4 pk;
                pk[0] = (short)f2b(u[ei][ch][0]); pk[1] = (short)f2b(u[ei][ch][1]);
                pk[2] = (short)f2b(u[ei][ch][2]); pk[3] = (short)f2b(u[ei][ch][3]);
                *(s16x4*)((char*)u_scr + rbase + l15 * 80 + (ch << 5) + (kg << 3)) = pk;
            }
        }
#pragma unroll
        for (int ei = 0; ei < 2; ei++) {
            int e = (wv << 1) + ei;
            int rbase = ((wv << 1) + ei) * 1280;
            s16x8 ub = *(const s16x8*)((char*)u_scr + rbase + l15 * 80 + (kg << 4));
#pragma unroll
            for (int oh = 0; oh < 2; oh++) {
                int o = (oh << 4) + l15;
                int abyte = (e << 11) + (o << 6) + (kg << 4);
                abyte ^= ((e ^ o) & 7) << 4;
                s16x8 ra = *(const s16x8*)((char*)rad_lds + abyte);
                acc[ei][oh] =
                    __builtin_amdgcn_mfma_f32_16x16x32_bf16(ra, ub, acc[ei][oh], 0, 0, 0);
            }
        }
        __syncthreads();
    }

    // ---- epilogue: atomic segment-sum into out[dst][o][s] ----
#pragma unroll
    for (int ei = 0; ei < 2; ei++) {
        int e = (wv << 1) + ei;
        int d = dst[eb + e];
        float* op = &out[(size_t)d * (CC * SD)];
#pragma unroll
        for (int oh = 0; oh < 2; oh++) {
#pragma unroll
            for (int r = 0; r < 4; r++) {
                int o = (oh << 4) + (kg << 2) + r;
                atomicAdd(&op[o * SD + l15], acc[ei][oh][r]);
            }
        }
    }
}

// ---------------- K3: self-interaction out[n][o][s] += deg[n]*sum_c ks[o][c]*nf[n][c][j] ----
__global__ __launch_bounds__(256) void k_self(
    const float* __restrict__ nf0, const float* __restrict__ nf1,
    const float* __restrict__ nf2, const float* __restrict__ nf3,
    const float* __restrict__ ks0, const float* __restrict__ ks1,
    const float* __restrict__ ks2, const float* __restrict__ ks3,
    const int* __restrict__ deg, float* __restrict__ out) {
    int idx = blockIdx.x * 256 + threadIdx.x;   // over N*32*16 = 524288
    if (idx >= NN * CC * SD) return;
    int n = idx >> 9;
    int rem = idx & 511;
    int o = rem >> 4;
    int s = rem & 15;
    const float* nf;
    const float* ks;
    int dim, off;
    if (s < 1) { nf = nf0; ks = ks0; dim = 1; off = 0; }
    else if (s < 4) { nf = nf1; ks = ks1; dim = 3; off = 1; }
    else if (s < 9) { nf = nf2; ks = ks2; dim = 5; off = 4; }
    else { nf = nf3; ks = ks3; dim = 7; off = 9; }
    int j = s - off;
    float acc = 0.f;
#pragma unroll
    for (int c = 0; c < CC; c++) acc += ks[o * CC + c] * nf[(n * CC + c) * dim + j];
    out[idx] += (float)deg[n] * acc;
}

extern "C" void kernel_launch(void* const* d_in, const int* in_sizes, int n_in,
                              void* d_out, int out_size, void* d_ws, size_t ws_size,
                              hipStream_t stream) {
    const float* nf0 = (const float*)d_in[0];
    const float* nf1 = (const float*)d_in[1];
    const float* nf2 = (const float*)d_in[2];
    const float* nf3 = (const float*)d_in[3];
    const float* ef = (const float*)d_in[4];
    const float* basis = (const float*)d_in[5];
    const int* src = (const int*)d_in[6];
    const int* dst = (const int*)d_in[7];
    const float* w1 = (const float*)d_in[8];
    const float* b1 = (const float*)d_in[9];
    const float* w2 = (const float*)d_in[10];
    const float* b2 = (const float*)d_in[11];
    const float* w3 = (const float*)d_in[12];
    const float* ks0 = (const float*)d_in[13];
    const float* ks1 = (const float*)d_in[14];
    const float* ks2 = (const float*)d_in[15];
    const float* ks3 = (const float*)d_in[16];
    float* out = (float*)d_out;

    // workspace layout
    unsigned short* h2 = (unsigned short*)d_ws;                    // 256 KB
    int* deg = (int*)((char*)d_ws + EE * MIDC * 2);                // 4 KB
    unsigned short* w3t2 = (unsigned short*)((char*)d_ws + EE * MIDC * 2 + 4096);  // 2.88 MB

    hipMemsetAsync(d_out, 0, (size_t)out_size * sizeof(float), stream);
    hipMemsetAsync(deg, 0, NN * sizeof(int), stream);

    k_w3t2<<<128, 256, 0, stream>>>(w3, w3t2);
    k_h<<<EE / 256, 256, 0, stream>>>(ef, w1, b1, w2, b2, dst, h2, deg);
    k_main<<<(EE / EB) * NFQ, 512, 0, stream>>>(nf0, nf1, nf2, nf3, basis, src, dst,
                                                h2, w3t2, out);
    k_self<<<(NN * CC * SD) / 256, 256, 0, stream>>>(nf0, nf1, nf2, nf3, ks0, ks1,
                                                     ks2, ks3, deg, out);
}

// Round 5
// 112.616 us; speedup vs baseline: 1.2208x; 1.2208x over previous
//
#include <hip/hip_runtime.h>
#include <hip/hip_bf16.h>

#define NN 1024
#define EE 4096
#define CC 32     // channels C
#define SD 16     // SUM_DIM
#define FQ 44     // FREQ_SUM
#define MIDC 32   // MLP mid
#define EB 16     // edges per workgroup
#define NFQ 2     // f-range split
#define FPB 22    // f per block

typedef short s16x4 __attribute__((ext_vector_type(4)));
typedef short s16x8 __attribute__((ext_vector_type(8)));
typedef float fx4 __attribute__((ext_vector_type(4)));

__device__ __forceinline__ unsigned short f2b(float x) {
    __hip_bfloat16 b = __float2bfloat16(x);
    return *reinterpret_cast<unsigned short*>(&b);
}

__device__ __forceinline__ s16x4 pack4(float a, float b, float c, float d) {
    s16x4 r;
    r[0] = (short)f2b(a); r[1] = (short)f2b(b);
    r[2] = (short)f2b(c); r[3] = (short)f2b(d);
    return r;
}

// 16x16x16 bf16 MFMA. NOTE: __has_builtin on the HOST pass returns false for
// amdgcn builtins, so the selection must be guarded by __HIP_DEVICE_COMPILE__
// (host never executes this body).
__device__ __forceinline__ fx4 mfma16(s16x4 a, s16x4 b, fx4 c) {
#if defined(__HIP_DEVICE_COMPILE__)
#if __has_builtin(__builtin_amdgcn_mfma_f32_16x16x16_bf16)
    return __builtin_amdgcn_mfma_f32_16x16x16_bf16(a, b, c, 0, 0, 0);
#else
    return __builtin_amdgcn_mfma_f32_16x16x16bf16_1k(a, b, c, 0, 0, 0);
#endif
#else
    return c;
#endif
}

// ---------------- K0: w3 (m, o*1408 + c*44 + f) -> w3t2[f][o][c][m] bf16 ----------------
__global__ __launch_bounds__(256) void k_w3t2(const float* __restrict__ w3,
                                              unsigned short* __restrict__ w3t2) {
    int tid = blockIdx.x * 256 + threadIdx.x;   // 32768 threads
    int m = tid & 31;
    int o = (tid >> 5) & 31;
    int c = tid >> 10;
    const float* rp = &w3[(size_t)m * 45056 + o * 1408 + c * 44];
    float v[44];
#pragma unroll
    for (int q = 0; q < 11; q++) {
        float4 t4 = *(const float4*)(rp + q * 4);
        v[q * 4 + 0] = t4.x; v[q * 4 + 1] = t4.y;
        v[q * 4 + 2] = t4.z; v[q * 4 + 3] = t4.w;
    }
#pragma unroll
    for (int f = 0; f < FQ; f++) {
        w3t2[(((size_t)f * CC + o) * CC + c) * CC + m] = f2b(v[f]);
    }
}

// ---------------- K1: h2 = bf16(relu(relu(inv@w1+b1)@w2+b2)), deg counts ----------------
__global__ __launch_bounds__(256) void k_h(const float* __restrict__ ef,
                                           const float* __restrict__ w1,
                                           const float* __restrict__ b1,
                                           const float* __restrict__ w2,
                                           const float* __restrict__ b2,
                                           const int* __restrict__ dst,
                                           unsigned short* __restrict__ h2,
                                           int* __restrict__ deg) {
    int e = blockIdx.x * 256 + threadIdx.x;
    if (e >= EE) return;
    float i0 = ef[e * 2 + 0], i1 = ef[e * 2 + 1];
    float h1[MIDC];
#pragma unroll
    for (int j = 0; j < MIDC; j++) {
        float v = i0 * w1[j] + i1 * w1[MIDC + j] + b1[j];
        h1[j] = v > 0.f ? v : 0.f;
    }
    for (int j = 0; j < MIDC; j++) {
        float v = b2[j];
#pragma unroll
        for (int m = 0; m < MIDC; m++) v += h1[m] * w2[m * MIDC + j];
        v = v > 0.f ? v : 0.f;
        h2[e * MIDC + j] = f2b(v);
    }
    atomicAdd(&deg[dst[e]], 1);
}

// ---------------- K2: fused MFMA main kernel ----------------
// grid = 512: blockIdx -> (e-group of 16) x (f-half of 22). 512 threads = 8 waves.
// Per wave: 2 edges. Only LDS = rad_lds (32 KB), swizzled conflict-free.
__global__ __launch_bounds__(512, 4) void k_main(
    const float* __restrict__ nf0, const float* __restrict__ nf1,
    const float* __restrict__ nf2, const float* __restrict__ nf3,
    const float* __restrict__ basis, const int* __restrict__ src,
    const int* __restrict__ dst, const unsigned short* __restrict__ h2,
    const unsigned short* __restrict__ w3t2, float* __restrict__ out) {
    __shared__ __align__(16) unsigned short rad_lds[EB * CC * CC];   // 32768 B

    int t = threadIdx.x;
    int wv = t >> 6;
    int l = t & 63;
    int l15 = l & 15;
    int kg = l >> 4;            // k-group 0..3
    int eg = blockIdx.x >> 1;
    int fq = blockIdx.x & 1;
    int eb = eg * EB;
    int f0 = fq * FPB;

    // ---- h2 fragment (B of rad mfma, K=32): lane: e=l15 (col), k=m=kg*8..+8 ----
    s16x8 h2frag = *(const s16x8*)(h2 + ((size_t)(eb + l15) * MIDC + (kg << 3)));

    // ---- feats A-frags (K=16): fa[ei][ch]: row c=ch*16+l15, k=i=kg*4..+4, direct from global ----
    s16x4 fa[2][2];
#pragma unroll
    for (int ei = 0; ei < 2; ei++) {
        int sn = src[eb + (wv << 1) + ei];
#pragma unroll
        for (int ch = 0; ch < 2; ch++) {
            int c = (ch << 4) + l15;
            s16x4 v;
#pragma unroll
            for (int j = 0; j < 4; j++) {
                int i = (kg << 2) + j;
                float x;
                if (i < 1) x = nf0[sn * CC + c];
                else if (i < 4) x = nf1[(sn * CC + c) * 3 + (i - 1)];
                else if (i < 9) x = nf2[(sn * CC + c) * 5 + (i - 4)];
                else x = nf3[(sn * CC + c) * 7 + (i - 9)];
                v[j] = (short)f2b(x);
            }
            fa[ei][ch] = v;
        }
    }

    // ---- precompute swizzled LDS byte addresses (f-invariant) ----
    // layout: byte = e<<11 | o<<6 | ch<<5 | kg<<3, then ^= ((e^o)&15)<<3  (bijective,
    // per-16-lane-quarter all 16 bank-pairs distinct on both write and read)
    int radw[8];
#pragma unroll
    for (int j = 0; j < 8; j++) {
        int o = (wv << 2) + (j >> 1), ch = j & 1;
        int b = (l15 << 11) | (o << 6) | (ch << 5) | (kg << 3);
        radw[j] = b ^ (((l15 ^ o) & 15) << 3);
    }
    int rada[2][2][2];
#pragma unroll
    for (int ei = 0; ei < 2; ei++) {
        int e = (wv << 1) + ei;
#pragma unroll
        for (int oh = 0; oh < 2; oh++) {
            int o = (oh << 4) + l15;
#pragma unroll
            for (int ch = 0; ch < 2; ch++) {
                int b = (e << 11) | (o << 6) | (ch << 5) | (kg << 3);
                rada[ei][oh][ch] = b ^ (((e ^ o) & 15) << 3);
            }
        }
    }

    fx4 acc[2][2];
#pragma unroll
    for (int q = 0; q < 4; q++) acc[q >> 1][q & 1] = (fx4){0.f, 0.f, 0.f, 0.f};
    fx4 zz = (fx4){0.f, 0.f, 0.f, 0.f};

    // ---- prefetch registers (single-buffered; reloaded mid-body for f+1) ----
    s16x8 w[8];
    float pf[2][4];

#define LOAD_W(F)                                                                       \
    {                                                                                   \
        _Pragma("unroll") for (int j = 0; j < 8; j++) {                                 \
            int o_ = (wv << 2) + (j >> 1), ch_ = j & 1;                                 \
            w[j] = *(const s16x8*)(w3t2 +                                               \
                ((((size_t)(F) * CC + o_) * CC + (ch_ << 4) + l15) * CC + (kg << 3)));  \
        }                                                                               \
    }
#define LOAD_PF(F)                                                                      \
    {                                                                                   \
        _Pragma("unroll") for (int ei_ = 0; ei_ < 2; ei_++) {                           \
            const float* bp = basis +                                                   \
                (((size_t)(eb + (wv << 1) + ei_) * SD + (kg << 2)) * FQ + (F)) * SD +   \
                l15;                                                                    \
            _Pragma("unroll") for (int j = 0; j < 4; j++)                               \
                pf[ei_][j] = bp[(size_t)j * (FQ * SD)];                                 \
        }                                                                               \
    }

    LOAD_W(f0);
    LOAD_PF(f0);

    for (int fi = 0; fi < FPB; fi++) {
        // ---- rad: 8x mfma K=32 (w regs) -> pack -> swizzled LDS write ----
#pragma unroll
        for (int j = 0; j < 8; j++) {
            fx4 cf = __builtin_amdgcn_mfma_f32_16x16x32_bf16(w[j], h2frag, zz, 0, 0, 0);
            *(s16x4*)((char*)rad_lds + radw[j]) = pack4(cf[0], cf[1], cf[2], cf[3]);
        }
        // ---- basis B-frags for U (consume pf), then issue next-f prefetches ----
        s16x4 bbf[2];
#pragma unroll
        for (int ei = 0; ei < 2; ei++)
            bbf[ei] = pack4(pf[ei][0], pf[ei][1], pf[ei][2], pf[ei][3]);
        int fn = (fi + 1 < FPB) ? f0 + fi + 1 : f0;
        LOAD_W(fn);
        LOAD_PF(fn);
        __syncthreads();

        // ---- U (K=16) -> in-lane repack -> final (K=16 per c-half) ----
#pragma unroll
        for (int ei = 0; ei < 2; ei++) {
#pragma unroll
            for (int ch = 0; ch < 2; ch++) {
                fx4 u = mfma16(fa[ei][ch], bbf[ei], zz);
                s16x4 ub = pack4(u[0], u[1], u[2], u[3]);
#pragma unroll
                for (int oh = 0; oh < 2; oh++) {
                    s16x4 ra = *(const s16x4*)((char*)rad_lds + rada[ei][oh][ch]);
                    acc[ei][oh] = mfma16(ra, ub, acc[ei][oh]);
                }
            }
        }
        __syncthreads();
    }

    // ---- epilogue: atomic segment-sum into out[dst][o][s] ----
#pragma unroll
    for (int ei = 0; ei < 2; ei++) {
        int e = (wv << 1) + ei;
        int d = dst[eb + e];
        float* op = &out[(size_t)d * (CC * SD)];
#pragma unroll
        for (int oh = 0; oh < 2; oh++) {
#pragma unroll
            for (int r = 0; r < 4; r++) {
                int o = (oh << 4) + (kg << 2) + r;
                atomicAdd(&op[o * SD + l15], acc[ei][oh][r]);
            }
        }
    }
}

// ---------------- K3: self-interaction out[n][o][s] += deg[n]*sum_c ks[o][c]*nf[n][c][j] ----
__global__ __launch_bounds__(256) void k_self(
    const float* __restrict__ nf0, const float* __restrict__ nf1,
    const float* __restrict__ nf2, const float* __restrict__ nf3,
    const float* __restrict__ ks0, const float* __restrict__ ks1,
    const float* __restrict__ ks2, const float* __restrict__ ks3,
    const int* __restrict__ deg, float* __restrict__ out) {
    int idx = blockIdx.x * 256 + threadIdx.x;   // over N*32*16 = 524288
    if (idx >= NN * CC * SD) return;
    int n = idx >> 9;
    int rem = idx & 511;
    int o = rem >> 4;
    int s = rem & 15;
    const float* nf;
    const float* ks;
    int dim, off;
    if (s < 1) { nf = nf0; ks = ks0; dim = 1; off = 0; }
    else if (s < 4) { nf = nf1; ks = ks1; dim = 3; off = 1; }
    else if (s < 9) { nf = nf2; ks = ks2; dim = 5; off = 4; }
    else { nf = nf3; ks = ks3; dim = 7; off = 9; }
    int j = s - off;
    float acc = 0.f;
#pragma unroll
    for (int c = 0; c < CC; c++) acc += ks[o * CC + c] * nf[(n * CC + c) * dim + j];
    out[idx] += (float)deg[n] * acc;
}

extern "C" void kernel_launch(void* const* d_in, const int* in_sizes, int n_in,
                              void* d_out, int out_size, void* d_ws, size_t ws_size,
                              hipStream_t stream) {
    const float* nf0 = (const float*)d_in[0];
    const float* nf1 = (const float*)d_in[1];
    const float* nf2 = (const float*)d_in[2];
    const float* nf3 = (const float*)d_in[3];
    const float* ef = (const float*)d_in[4];
    const float* basis = (const float*)d_in[5];
    const int* src = (const int*)d_in[6];
    const int* dst = (const int*)d_in[7];
    const float* w1 = (const float*)d_in[8];
    const float* b1 = (const float*)d_in[9];
    const float* w2 = (const float*)d_in[10];
    const float* b2 = (const float*)d_in[11];
    const float* w3 = (const float*)d_in[12];
    const float* ks0 = (const float*)d_in[13];
    const float* ks1 = (const float*)d_in[14];
    const float* ks2 = (const float*)d_in[15];
    const float* ks3 = (const float*)d_in[16];
    float* out = (float*)d_out;

    // workspace layout
    unsigned short* h2 = (unsigned short*)d_ws;                    // 256 KB
    int* deg = (int*)((char*)d_ws + EE * MIDC * 2);                // 4 KB
    unsigned short* w3t2 = (unsigned short*)((char*)d_ws + EE * MIDC * 2 + 4096);  // 2.88 MB

    (void)hipMemsetAsync(d_out, 0, (size_t)out_size * sizeof(float), stream);
    (void)hipMemsetAsync(deg, 0, NN * sizeof(int), stream);

    k_w3t2<<<128, 256, 0, stream>>>(w3, w3t2);
    k_h<<<EE / 256, 256, 0, stream>>>(ef, w1, b1, w2, b2, dst, h2, deg);
    k_main<<<(EE / EB) * NFQ, 512, 0, stream>>>(nf0, nf1, nf2, nf3, basis, src, dst,
                                                h2, w3t2, out);
    k_self<<<(NN * CC * SD) / 256, 256, 0, stream>>>(nf0, nf1, nf2, nf3, ks0, ks1,
                                                     ks2, ks3, deg, out);
}